// Round 7
// baseline (115.294 us; speedup 1.0000x reference)
//
#include <hip/hip_runtime.h>

typedef __attribute__((ext_vector_type(4))) float f32x4;
typedef __attribute__((ext_vector_type(16))) float f32x16;
typedef __attribute__((ext_vector_type(8))) __bf16 bf16x8;
typedef __attribute__((ext_vector_type(4))) __bf16 bf16x4;
typedef __attribute__((ext_vector_type(4))) unsigned u32x4;
typedef __attribute__((ext_vector_type(2))) unsigned u32x2;

static __device__ __forceinline__ f32x4 mfma16(bf16x8 a, bf16x8 b, f32x4 c) {
    return __builtin_amdgcn_mfma_f32_16x16x32_bf16(a, b, c, 0, 0, 0);
}
static __device__ __forceinline__ f32x16 mfma32(bf16x8 a, bf16x8 b, f32x16 c) {
    return __builtin_amdgcn_mfma_f32_32x32x16_bf16(a, b, c, 0, 0, 0);
}
static __device__ __forceinline__ unsigned pk_bf16(float a, float b) {
    unsigned lo = __builtin_bit_cast(unsigned short, (__bf16)a);
    unsigned hh = __builtin_bit_cast(unsigned short, (__bf16)b);
    return lo | (hh << 16);
}

// Q pre-scale: 1/sqrt(64) * log2(e)  (exp2 applied directly to S, shift-free)
#define QSCALE 0.18033688f

// ---------------------------------------------------------------------------
// 1) fp32 -> bf16 elementwise convert (vectorized)
// ---------------------------------------------------------------------------
__global__ __launch_bounds__(256) void cvt_f32_bf16(const float* __restrict__ in,
                                                    __bf16* __restrict__ out, int n4) {
    int i = blockIdx.x * 256 + threadIdx.x;
    if (i < n4) {
        f32x4 v = ((const f32x4*)in)[i];
        bf16x4 o;
#pragma unroll
        for (int j = 0; j < 4; j++) o[j] = (__bf16)v[j];
        ((bf16x4*)out)[i] = o;
    }
}

// ---------------------------------------------------------------------------
// 2) fp32 (R x C) -> bf16 transposed (C x R)
// ---------------------------------------------------------------------------
__global__ __launch_bounds__(256) void transpose_bf16(const float* __restrict__ in,
                                                      __bf16* __restrict__ out,
                                                      int R, int C) {
    __shared__ float t[32][33];
    int bx = blockIdx.x * 32;
    int by = blockIdx.y * 32;
    int tx = threadIdx.x, ty = threadIdx.y;
#pragma unroll
    for (int k = 0; k < 32; k += 8)
        t[ty + k][tx] = in[(size_t)(by + ty + k) * C + bx + tx];
    __syncthreads();
#pragma unroll
    for (int k = 0; k < 32; k += 8)
        out[(size_t)(bx + ty + k) * R + by + tx] = (__bf16)t[tx][ty + k];
}

// ---------------------------------------------------------------------------
// 3) bf16 GEMM, orientation-B (rows = features, cols = tokens), 128x128 tile,
//    BK=64, 4 waves. DOUBLE-BUFFERED single-barrier K-loop (T3-minimum):
//    stage tile t+1 BEFORE computing tile t; one __syncthreads per tile
//    (its implicit vmcnt(0) lands after the MFMA phase -> staging latency
//    hidden under compute). LDS = 64 KiB -> 2 blocks/CU.
//    MODE 0: store out[token][feature] fp32 float4.
//    MODE 1: scatter QKV fragments (Q scaled; Qf/Kf bf16x4, Vf scalar).
// ---------------------------------------------------------------------------
#define BM 128
#define BN 128
#define BKG 64

template <int MODE>
__global__ __launch_bounds__(256) void gemm_bt(const __bf16* __restrict__ A,
                                               const __bf16* __restrict__ Bt,
                                               int M, int N, int K,
                                               float* __restrict__ Cout,
                                               __bf16* __restrict__ Qf,
                                               __bf16* __restrict__ Kf,
                                               __bf16* __restrict__ Vf) {
    __shared__ __attribute__((aligned(16))) __bf16 As[2][BM * BKG];
    __shared__ __attribute__((aligned(16))) __bf16 Bs[2][BN * BKG];
    int tid = threadIdx.x;
    int wave = tid >> 6, lane = tid & 63;
    int lrow = lane & 15, lgrp = lane >> 4;
    // XCD swizzle (bijective: gridDim.x % 8 == 0)
    int chunk = gridDim.x >> 3;
    int bid = blockIdx.x;
    int swz = (bid & 7) * chunk + (bid >> 3);
    int nbx = N >> 7;
    int m0 = (swz / nbx) * BM, n0 = (swz % nbx) * BN;
    int wm = (wave >> 1) * 64, wn = (wave & 1) * 64;

    f32x4 acc[4][4];
#pragma unroll
    for (int i = 0; i < 4; i++)
#pragma unroll
        for (int j = 0; j < 4; j++) acc[i][j] = (f32x4){0.f, 0.f, 0.f, 0.f};

    int srow = tid >> 3;
    int gch = (tid & 7) ^ (srow & 7);
    const __bf16* aSrc = A + (size_t)(m0 + srow) * K + gch * 8;
    const __bf16* bSrc = Bt + (size_t)(n0 + srow) * K + gch * 8;

    auto STAGE = [&](int k0, int b) {
#pragma unroll
        for (int c = 0; c < 4; c++) {
            __builtin_amdgcn_global_load_lds(
                (const __attribute__((address_space(1))) void*)(aSrc + k0 + (size_t)c * 32 * K),
                (__attribute__((address_space(3))) void*)(As[b] + (c * 256 + wave * 64) * 8),
                16, 0, 0);
        }
#pragma unroll
        for (int c = 0; c < 4; c++) {
            __builtin_amdgcn_global_load_lds(
                (const __attribute__((address_space(1))) void*)(bSrc + k0 + (size_t)c * 32 * K),
                (__attribute__((address_space(3))) void*)(Bs[b] + (c * 256 + wave * 64) * 8),
                16, 0, 0);
        }
    };

    int nk = K >> 6;
    STAGE(0, 0);
    __syncthreads();  // drains the prologue stage

    for (int t = 0; t < nk; t++) {
        int cur = t & 1;
        if (t + 1 < nk) STAGE((t + 1) << 6, cur ^ 1);  // prefetch next tile
#pragma unroll
        for (int kk = 0; kk < 2; kk++) {
            bf16x8 af[4], bfr[4];
#pragma unroll
            for (int mt = 0; mt < 4; mt++) {
                int row = wm + mt * 16 + lrow;
                int slot = row * 8 + ((4 * kk + lgrp) ^ (row & 7));
                af[mt] = *(const bf16x8*)(As[cur] + slot * 8);
            }
#pragma unroll
            for (int nt = 0; nt < 4; nt++) {
                int row = wn + nt * 16 + lrow;
                int slot = row * 8 + ((4 * kk + lgrp) ^ (row & 7));
                bfr[nt] = *(const bf16x8*)(Bs[cur] + slot * 8);
            }
#pragma unroll
            for (int mt = 0; mt < 4; mt++)
#pragma unroll
                for (int nt = 0; nt < 4; nt++)
                    acc[mt][nt] = mfma16(af[mt], bfr[nt], acc[mt][nt]);
        }
        __syncthreads();  // vmcnt(0)+lgkmcnt(0) after MFMA phase; buf swap safe
    }

#pragma unroll
    for (int mt = 0; mt < 4; mt++) {
#pragma unroll
        for (int nt = 0; nt < 4; nt++) {
            int f0 = m0 + wm + mt * 16 + lgrp * 4;  // 4 consecutive features
            int t = n0 + wn + nt * 16 + lrow;       // token
            if (MODE == 0) {
                *(f32x4*)(Cout + (size_t)t * M + f0) = acc[mt][nt];
            } else {
                int which = f0 >> 10, hn = f0 & 1023;
                int h = hn >> 6, d0 = hn & 63;
                int b = t >> 11, li = t & 2047;
                int bh = b * 16 + h, c = li >> 5, tl = li & 31;
                size_t bhbase = (size_t)bh * 131072;
                if (which == 2) {
                    int ks = tl >> 4, hv = (tl >> 3) & 1, jv = tl & 7;
                    size_t base =
                        bhbase + ((size_t)(c * 4 + ks * 2 + hv) * 64 + d0) * 8 + jv;
#pragma unroll
                    for (int r = 0; r < 4; r++)
                        Vf[base + (size_t)r * 8] = (__bf16)acc[mt][nt][r];
                } else {
                    int st = d0 >> 4, hv = (d0 >> 3) & 1, j0 = d0 & 7;
                    size_t idx =
                        bhbase + ((size_t)(c * 8 + st * 2 + hv) * 32 + tl) * 8 + j0;
                    bf16x4 pv;
                    if (which == 0) {
#pragma unroll
                        for (int r = 0; r < 4; r++)
                            pv[r] = (__bf16)(acc[mt][nt][r] * QSCALE);
                        *(bf16x4*)(Qf + idx) = pv;
                    } else {
#pragma unroll
                        for (int r = 0; r < 4; r++) pv[r] = (__bf16)acc[mt][nt][r];
                        *(bf16x4*)(Kf + idx) = pv;
                    }
                }
            }
        }
    }
}

// ---------------------------------------------------------------------------
// 4) Causal flash attention, swapped-QK^T, 32x32x16 MFMA, fragment-swizzled
//    Q/K/V. 4 waves split the K chunks; shift-free softmax => partial (O, ls)
//    combine is a pure SUM. Load-balanced: each block owns strip PAIR
//    (s, 63-s) -> exactly 65 chunk-units per block, uniform duration.
// ---------------------------------------------------------------------------
template <bool MASKED>
static __device__ __forceinline__ void attn_chunk(
    int c, int ql, int hi, const __bf16* __restrict__ Kp,
    const __bf16* __restrict__ Vp, const bf16x8 (&qf)[4],
    f32x16& o0, f32x16& o1, float& ls) {
    const __bf16* kb = Kp + ((size_t)c * 8 + hi) * 256 + ql * 8;
    bf16x8 kf[4];
#pragma unroll
    for (int st = 0; st < 4; st++) kf[st] = *(const bf16x8*)(kb + st * 512);
    const __bf16* vb = Vp + ((size_t)c * 4 + hi) * 512 + ql * 8;
    bf16x8 v00 = *(const bf16x8*)(vb);
    bf16x8 v01 = *(const bf16x8*)(vb + 256);
    bf16x8 v10 = *(const bf16x8*)(vb + 1024);
    bf16x8 v11 = *(const bf16x8*)(vb + 1280);

    f32x16 sa;
#pragma unroll
    for (int r = 0; r < 16; r++) sa[r] = 0.f;
#pragma unroll
    for (int st = 0; st < 4; st++) sa = mfma32(kf[st], qf[st], sa);

    float p[16];
    float psum = 0.f;
#pragma unroll
    for (int r = 0; r < 16; r++) {
        float s = sa[r];
        if (MASKED) {
            int krel = (r & 3) + 8 * (r >> 2) + 4 * hi;
            if (krel > ql) s = -1e30f;
        }
        float pv = __builtin_amdgcn_exp2f(s);
        p[r] = pv;
        psum += pv;
    }
    u32x2 ps = __builtin_amdgcn_permlane32_swap(
        __builtin_bit_cast(unsigned, psum), __builtin_bit_cast(unsigned, psum),
        false, false);
    psum += __builtin_bit_cast(float, hi ? ps[0] : ps[1]);
    ls += psum;

    unsigned w[8];
#pragma unroll
    for (int i = 0; i < 8; i++) w[i] = pk_bf16(p[2 * i], p[2 * i + 1]);
    u32x2 r02 = __builtin_amdgcn_permlane32_swap(w[0], w[2], false, false);
    u32x2 r13 = __builtin_amdgcn_permlane32_swap(w[1], w[3], false, false);
    u32x2 r46 = __builtin_amdgcn_permlane32_swap(w[4], w[6], false, false);
    u32x2 r57 = __builtin_amdgcn_permlane32_swap(w[5], w[7], false, false);
    bf16x8 pa0 = __builtin_bit_cast(bf16x8, (u32x4){r02[0], r13[0], r02[1], r13[1]});
    bf16x8 pa1 = __builtin_bit_cast(bf16x8, (u32x4){r46[0], r57[0], r46[1], r57[1]});

    o0 = mfma32(pa0, v00, o0);
    o1 = mfma32(pa0, v01, o1);
    o0 = mfma32(pa1, v10, o0);
    o1 = mfma32(pa1, v11, o1);
}

static __device__ __forceinline__ void attn_strip(
    int strip, int bh, int wave, int lane, int ql, int hi,
    const __bf16* __restrict__ Qp, const __bf16* __restrict__ Kp,
    const __bf16* __restrict__ Vp, __bf16* __restrict__ Ob,
    float (*comb)[64][33]) {
    int q0 = strip * 32;
    const __bf16* qb = Qp + ((size_t)strip * 8 + hi) * 256 + ql * 8;
    bf16x8 qf[4];
#pragma unroll
    for (int st = 0; st < 4; st++) qf[st] = *(const bf16x8*)(qb + st * 512);

    f32x16 o0, o1;
#pragma unroll
    for (int r = 0; r < 16; r++) { o0[r] = 0.f; o1[r] = 0.f; }
    float ls = 0.f;

    for (int c = wave; c < strip; c += 4)
        attn_chunk<false>(c, ql, hi, Kp, Vp, qf, o0, o1, ls);
    if ((strip & 3) == wave)
        attn_chunk<true>(strip, ql, hi, Kp, Vp, qf, o0, o1, ls);

    // combine partials: waves 1..3 -> slabs, wave 0 sums + writes
    if (wave >= 1) {
        float* sl = &comb[wave - 1][lane][0];
#pragma unroll
        for (int r = 0; r < 16; r++) { sl[r] = o0[r]; sl[16 + r] = o1[r]; }
        sl[32] = ls;
    }
    __syncthreads();
    if (wave == 0) {
#pragma unroll
        for (int s = 0; s < 3; s++) {
            const float* sl = &comb[s][lane][0];
#pragma unroll
            for (int r = 0; r < 16; r++) { o0[r] += sl[r]; o1[r] += sl[16 + r]; }
            ls += sl[32];
        }
        float inv = 1.0f / ls;
        int b = bh >> 4, h = bh & 15;
#pragma unroll
        for (int r = 0; r < 16; r++) {
            int crow = (r & 3) + 8 * (r >> 2) + 4 * hi;
            float ibc = __shfl(inv, crow);
            size_t base = ((size_t)(b * 2048 + q0 + crow)) * 1024 + h * 64;
            Ob[base + ql] = (__bf16)(o0[r] * ibc);
            Ob[base + 32 + ql] = (__bf16)(o1[r] * ibc);
        }
    }
    __syncthreads();  // protect slabs before next strip reuses them
}

__global__ __launch_bounds__(256) void attn_fwd6(const __bf16* __restrict__ Qf,
                                                 const __bf16* __restrict__ Kf,
                                                 const __bf16* __restrict__ Vf,
                                                 __bf16* __restrict__ Ob) {
    __shared__ float comb[3][64][33];
    int tid = threadIdx.x;
    int wave = tid >> 6, lane = tid & 63;
    int ql = lane & 31, hi = lane >> 5;
    // 1024 blocks = 8 xcd x 4 heads x 32 strip-pairs (uniform work: 65 units)
    int bid = blockIdx.x;
    int xcd = bid & 7, idx = bid >> 3;
    int bh = xcd * 4 + (idx >> 5);
    int pair = idx & 31;

    const __bf16* Qp = Qf + (size_t)bh * 131072;
    const __bf16* Kp = Kf + (size_t)bh * 131072;
    const __bf16* Vp = Vf + (size_t)bh * 131072;

    attn_strip(63 - pair, bh, wave, lane, ql, hi, Qp, Kp, Vp, Ob, comb);
    attn_strip(pair, bh, wave, lane, ql, hi, Qp, Kp, Vp, Ob, comb);
}

// ---------------------------------------------------------------------------
// launch
// ---------------------------------------------------------------------------
extern "C" void kernel_launch(void* const* d_in, const int* in_sizes, int n_in,
                              void* d_out, int out_size, void* d_ws, size_t ws_size,
                              hipStream_t stream) {
    const float* x = (const float*)d_in[0];       // (2, 2048, 1024)
    const float* w_qkv = (const float*)d_in[1];   // (1024, 3072)
    const float* w_out = (const float*)d_in[2];   // (1024, 1024)
    float* out = (float*)d_out;                   // (2, 2048, 1024)

    char* ws = (char*)d_ws;
    __bf16* xb    = (__bf16*)(ws);                        //  8 MB (4096x1024)
    __bf16* wqkvT = (__bf16*)(ws + (size_t)(8  << 20));   //  6 MB (3072x1024)
    __bf16* woutT = (__bf16*)(ws + (size_t)(14 << 20));   //  2 MB (1024x1024)
    __bf16* Qf    = (__bf16*)(ws + (size_t)(16 << 20));   //  8 MB
    __bf16* Kf    = (__bf16*)(ws + (size_t)(24 << 20));   //  8 MB
    __bf16* Vf    = (__bf16*)(ws + (size_t)(32 << 20));   //  8 MB
    __bf16* Ob    = (__bf16*)(ws + (size_t)(40 << 20));   //  8 MB (4096x1024)

    cvt_f32_bf16<<<4096, 256, 0, stream>>>(x, xb, 4096 * 1024 / 4);
    transpose_bf16<<<dim3(3072 / 32, 1024 / 32), dim3(32, 8), 0, stream>>>(w_qkv, wqkvT, 1024, 3072);
    transpose_bf16<<<dim3(1024 / 32, 1024 / 32), dim3(32, 8), 0, stream>>>(w_out, woutT, 1024, 1024);
    // QKV projection (M=3072 feats, N=4096 tokens)
    gemm_bt<1><<<768, 256, 0, stream>>>(
        wqkvT, xb, 3072, 4096, 1024, nullptr, Qf, Kf, Vf);
    attn_fwd6<<<1024, 256, 0, stream>>>(Qf, Kf, Vf, Ob);
    // output projection (M=1024 feats, N=4096 tokens)
    gemm_bt<0><<<256, 256, 0, stream>>>(
        woutT, Ob, 1024, 4096, 1024, out, nullptr, nullptr, nullptr);
}

// Round 8
// 111.978 us; speedup vs baseline: 1.0296x; 1.0296x over previous
//
#include <hip/hip_runtime.h>

typedef __attribute__((ext_vector_type(4))) float f32x4;
typedef __attribute__((ext_vector_type(16))) float f32x16;
typedef __attribute__((ext_vector_type(8))) __bf16 bf16x8;
typedef __attribute__((ext_vector_type(4))) __bf16 bf16x4;
typedef __attribute__((ext_vector_type(4))) unsigned u32x4;
typedef __attribute__((ext_vector_type(2))) unsigned u32x2;

static __device__ __forceinline__ f32x4 mfma16(bf16x8 a, bf16x8 b, f32x4 c) {
    return __builtin_amdgcn_mfma_f32_16x16x32_bf16(a, b, c, 0, 0, 0);
}
static __device__ __forceinline__ f32x16 mfma32(bf16x8 a, bf16x8 b, f32x16 c) {
    return __builtin_amdgcn_mfma_f32_32x32x16_bf16(a, b, c, 0, 0, 0);
}
static __device__ __forceinline__ unsigned pk_bf16(float a, float b) {
    unsigned lo = __builtin_bit_cast(unsigned short, (__bf16)a);
    unsigned hh = __builtin_bit_cast(unsigned short, (__bf16)b);
    return lo | (hh << 16);
}

// Q pre-scale: 1/sqrt(64) * log2(e)  (exp2 applied directly to S, shift-free)
#define QSCALE 0.18033688f

// ---------------------------------------------------------------------------
// 1) fp32 -> bf16 elementwise convert (vectorized)
// ---------------------------------------------------------------------------
__global__ __launch_bounds__(256) void cvt_f32_bf16(const float* __restrict__ in,
                                                    __bf16* __restrict__ out, int n4) {
    int i = blockIdx.x * 256 + threadIdx.x;
    if (i < n4) {
        f32x4 v = ((const f32x4*)in)[i];
        bf16x4 o;
#pragma unroll
        for (int j = 0; j < 4; j++) o[j] = (__bf16)v[j];
        ((bf16x4*)out)[i] = o;
    }
}

// ---------------------------------------------------------------------------
// 2) fp32 (R x C) -> bf16 transposed (C x R)
// ---------------------------------------------------------------------------
__global__ __launch_bounds__(256) void transpose_bf16(const float* __restrict__ in,
                                                      __bf16* __restrict__ out,
                                                      int R, int C) {
    __shared__ float t[32][33];
    int bx = blockIdx.x * 32;
    int by = blockIdx.y * 32;
    int tx = threadIdx.x, ty = threadIdx.y;
#pragma unroll
    for (int k = 0; k < 32; k += 8)
        t[ty + k][tx] = in[(size_t)(by + ty + k) * C + bx + tx];
    __syncthreads();
#pragma unroll
    for (int k = 0; k < 32; k += 8)
        out[(size_t)(bx + ty + k) * R + by + tx] = (__bf16)t[tx][ty + k];
}

// ---------------------------------------------------------------------------
// 3) bf16 GEMM (round-5 proven version): orientation-B, 128x128 tile, BK=64,
//    4 waves, single-buffer 2-barrier K-loop. MODE 0: fp32 float4 stores.
//    MODE 1: scatter QKV fragments (Q scaled; Qf/Kf bf16x4, Vf scalar).
// ---------------------------------------------------------------------------
#define BM 128
#define BN 128
#define BKG 64

template <int MODE>
__global__ __launch_bounds__(256) void gemm_bt(const __bf16* __restrict__ A,
                                               const __bf16* __restrict__ Bt,
                                               int M, int N, int K,
                                               float* __restrict__ Cout,
                                               __bf16* __restrict__ Qf,
                                               __bf16* __restrict__ Kf,
                                               __bf16* __restrict__ Vf) {
    __shared__ __attribute__((aligned(16))) __bf16 As[BM * BKG];
    __shared__ __attribute__((aligned(16))) __bf16 Bs[BN * BKG];
    int tid = threadIdx.x;
    int wave = tid >> 6, lane = tid & 63;
    int lrow = lane & 15, lgrp = lane >> 4;
    // XCD swizzle (bijective: gridDim.x % 8 == 0)
    int chunk = gridDim.x >> 3;
    int bid = blockIdx.x;
    int swz = (bid & 7) * chunk + (bid >> 3);
    int nbx = N >> 7;
    int m0 = (swz / nbx) * BM, n0 = (swz % nbx) * BN;
    int wm = (wave >> 1) * 64, wn = (wave & 1) * 64;

    f32x4 acc[4][4];
#pragma unroll
    for (int i = 0; i < 4; i++)
#pragma unroll
        for (int j = 0; j < 4; j++) acc[i][j] = (f32x4){0.f, 0.f, 0.f, 0.f};

    int srow = tid >> 3;
    int gch = (tid & 7) ^ (srow & 7);
    const __bf16* aSrc = A + (size_t)(m0 + srow) * K + gch * 8;
    const __bf16* bSrc = Bt + (size_t)(n0 + srow) * K + gch * 8;

    for (int k0 = 0; k0 < K; k0 += BKG) {
#pragma unroll
        for (int c = 0; c < 4; c++) {
            __builtin_amdgcn_global_load_lds(
                (const __attribute__((address_space(1))) void*)(aSrc + k0 + (size_t)c * 32 * K),
                (__attribute__((address_space(3))) void*)(As + (c * 256 + wave * 64) * 8),
                16, 0, 0);
        }
#pragma unroll
        for (int c = 0; c < 4; c++) {
            __builtin_amdgcn_global_load_lds(
                (const __attribute__((address_space(1))) void*)(bSrc + k0 + (size_t)c * 32 * K),
                (__attribute__((address_space(3))) void*)(Bs + (c * 256 + wave * 64) * 8),
                16, 0, 0);
        }
        __syncthreads();
#pragma unroll
        for (int kk = 0; kk < 2; kk++) {
            bf16x8 af[4], bfr[4];
#pragma unroll
            for (int mt = 0; mt < 4; mt++) {
                int row = wm + mt * 16 + lrow;
                int slot = row * 8 + ((4 * kk + lgrp) ^ (row & 7));
                af[mt] = *(const bf16x8*)(As + slot * 8);
            }
#pragma unroll
            for (int nt = 0; nt < 4; nt++) {
                int row = wn + nt * 16 + lrow;
                int slot = row * 8 + ((4 * kk + lgrp) ^ (row & 7));
                bfr[nt] = *(const bf16x8*)(Bs + slot * 8);
            }
#pragma unroll
            for (int mt = 0; mt < 4; mt++)
#pragma unroll
                for (int nt = 0; nt < 4; nt++)
                    acc[mt][nt] = mfma16(af[mt], bfr[nt], acc[mt][nt]);
        }
        __syncthreads();
    }

#pragma unroll
    for (int mt = 0; mt < 4; mt++) {
#pragma unroll
        for (int nt = 0; nt < 4; nt++) {
            int f0 = m0 + wm + mt * 16 + lgrp * 4;  // 4 consecutive features
            int t = n0 + wn + nt * 16 + lrow;       // token
            if (MODE == 0) {
                *(f32x4*)(Cout + (size_t)t * M + f0) = acc[mt][nt];
            } else {
                int which = f0 >> 10, hn = f0 & 1023;
                int h = hn >> 6, d0 = hn & 63;
                int b = t >> 11, li = t & 2047;
                int bh = b * 16 + h, c = li >> 5, tl = li & 31;
                size_t bhbase = (size_t)bh * 131072;
                if (which == 2) {
                    int ks = tl >> 4, hv = (tl >> 3) & 1, jv = tl & 7;
                    size_t base =
                        bhbase + ((size_t)(c * 4 + ks * 2 + hv) * 64 + d0) * 8 + jv;
#pragma unroll
                    for (int r = 0; r < 4; r++)
                        Vf[base + (size_t)r * 8] = (__bf16)acc[mt][nt][r];
                } else {
                    int st = d0 >> 4, hv = (d0 >> 3) & 1, j0 = d0 & 7;
                    size_t idx =
                        bhbase + ((size_t)(c * 8 + st * 2 + hv) * 32 + tl) * 8 + j0;
                    bf16x4 pv;
                    if (which == 0) {
#pragma unroll
                        for (int r = 0; r < 4; r++)
                            pv[r] = (__bf16)(acc[mt][nt][r] * QSCALE);
                        *(bf16x4*)(Qf + idx) = pv;
                    } else {
#pragma unroll
                        for (int r = 0; r < 4; r++) pv[r] = (__bf16)acc[mt][nt][r];
                        *(bf16x4*)(Kf + idx) = pv;
                    }
                }
            }
        }
    }
}

// ---------------------------------------------------------------------------
// 4) Causal flash attention, swapped-QK^T, 32x32x16 MFMA, fragment-swizzled
//    Q/K/V. 2048 blocks (one 32-row strip each), 4 waves split the K chunks.
//    Register-level K double-buffer: chunk c+4's K fragments are issued
//    BEFORE chunk c's compute (T14 issue-early); V loads sit at the top of
//    each compute so their latency hides under QK^T+softmax. setprio(1)
//    around MFMA clusters (T5). Shift-free softmax => partial (O, ls)
//    combine is a pure SUM, single-barrier combine tree.
// ---------------------------------------------------------------------------
template <bool MASKED>
static __device__ __forceinline__ void attn_compute(
    int c, int ql, int hi, const __bf16* __restrict__ Vp,
    const bf16x8 (&kf)[4], const bf16x8 (&qf)[4],
    f32x16& o0, f32x16& o1, float& ls) {
    // V fragments (used only after softmax -- latency hidden)
    const __bf16* vb = Vp + ((size_t)c * 4 + hi) * 512 + ql * 8;
    bf16x8 v00 = *(const bf16x8*)(vb);
    bf16x8 v01 = *(const bf16x8*)(vb + 256);
    bf16x8 v10 = *(const bf16x8*)(vb + 1024);
    bf16x8 v11 = *(const bf16x8*)(vb + 1280);

    f32x16 sa;
#pragma unroll
    for (int r = 0; r < 16; r++) sa[r] = 0.f;
    __builtin_amdgcn_s_setprio(1);
#pragma unroll
    for (int st = 0; st < 4; st++) sa = mfma32(kf[st], qf[st], sa);
    __builtin_amdgcn_s_setprio(0);

    float p[16];
    float psum = 0.f;
#pragma unroll
    for (int r = 0; r < 16; r++) {
        float s = sa[r];
        if (MASKED) {
            int krel = (r & 3) + 8 * (r >> 2) + 4 * hi;
            if (krel > ql) s = -1e30f;
        }
        float pv = __builtin_amdgcn_exp2f(s);
        p[r] = pv;
        psum += pv;
    }
    u32x2 ps = __builtin_amdgcn_permlane32_swap(
        __builtin_bit_cast(unsigned, psum), __builtin_bit_cast(unsigned, psum),
        false, false);
    psum += __builtin_bit_cast(float, hi ? ps[0] : ps[1]);
    ls += psum;

    unsigned w[8];
#pragma unroll
    for (int i = 0; i < 8; i++) w[i] = pk_bf16(p[2 * i], p[2 * i + 1]);
    u32x2 r02 = __builtin_amdgcn_permlane32_swap(w[0], w[2], false, false);
    u32x2 r13 = __builtin_amdgcn_permlane32_swap(w[1], w[3], false, false);
    u32x2 r46 = __builtin_amdgcn_permlane32_swap(w[4], w[6], false, false);
    u32x2 r57 = __builtin_amdgcn_permlane32_swap(w[5], w[7], false, false);
    bf16x8 pa0 = __builtin_bit_cast(bf16x8, (u32x4){r02[0], r13[0], r02[1], r13[1]});
    bf16x8 pa1 = __builtin_bit_cast(bf16x8, (u32x4){r46[0], r57[0], r46[1], r57[1]});

    __builtin_amdgcn_s_setprio(1);
    o0 = mfma32(pa0, v00, o0);
    o1 = mfma32(pa0, v01, o1);
    o0 = mfma32(pa1, v10, o0);
    o1 = mfma32(pa1, v11, o1);
    __builtin_amdgcn_s_setprio(0);
}

__global__ __launch_bounds__(256) void attn_fwd7(const __bf16* __restrict__ Qf,
                                                 const __bf16* __restrict__ Kf,
                                                 const __bf16* __restrict__ Vf,
                                                 __bf16* __restrict__ Ob) {
    __shared__ float comb[3][64][33];
    int tid = threadIdx.x;
    int wave = tid >> 6, lane = tid & 63;
    int ql = lane & 31, hi = lane >> 5;
    // XCD swizzle: 2048 blocks = 8 xcd x 4 heads x 64 strips (heavy first)
    int bid = blockIdx.x;
    int xcd = bid & 7, idx = bid >> 3;
    int bh = xcd * 4 + (idx >> 6);
    int strip = 63 - (idx & 63);
    int q0 = strip * 32;

    const __bf16* Qp = Qf + (size_t)bh * 131072;
    const __bf16* Kp = Kf + (size_t)bh * 131072;
    const __bf16* Vp = Vf + (size_t)bh * 131072;

    const __bf16* qb = Qp + ((size_t)strip * 8 + hi) * 256 + ql * 8;
    bf16x8 qf[4];
#pragma unroll
    for (int st = 0; st < 4; st++) qf[st] = *(const bf16x8*)(qb + st * 512);

    f32x16 o0, o1;
#pragma unroll
    for (int r = 0; r < 16; r++) { o0[r] = 0.f; o1[r] = 0.f; }
    float ls = 0.f;

    auto LOADK = [&](int c, bf16x8 (&kf)[4]) {
        const __bf16* kb = Kp + ((size_t)c * 8 + hi) * 256 + ql * 8;
#pragma unroll
        for (int st = 0; st < 4; st++) kf[st] = *(const bf16x8*)(kb + st * 512);
    };

    // pipelined full-chunk loop: prefetch K for c+4 before computing c
    int c = wave;
    bf16x8 kA[4], kB[4];
    if (c < strip) LOADK(c, kA);
    while (c < strip) {
        if (c + 4 < strip) LOADK(c + 4, kB);
        attn_compute<false>(c, ql, hi, Vp, kA, qf, o0, o1, ls);
        c += 4;
        if (c >= strip) break;
        if (c + 4 < strip) LOADK(c + 4, kA);
        attn_compute<false>(c, ql, hi, Vp, kB, qf, o0, o1, ls);
        c += 4;
    }
    // masked diagonal chunk
    if ((strip & 3) == wave) {
        bf16x8 kM[4];
        LOADK(strip, kM);
        attn_compute<true>(strip, ql, hi, Vp, kM, qf, o0, o1, ls);
    }

    // ---- combine partials: waves 1..3 -> slabs, single barrier, wave 0 sums
    if (wave >= 1) {
        float* sl = &comb[wave - 1][lane][0];
#pragma unroll
        for (int r = 0; r < 16; r++) { sl[r] = o0[r]; sl[16 + r] = o1[r]; }
        sl[32] = ls;
    }
    __syncthreads();
    if (wave == 0) {
#pragma unroll
        for (int s = 0; s < 3; s++) {
            const float* sl = &comb[s][lane][0];
#pragma unroll
            for (int r = 0; r < 16; r++) { o0[r] += sl[r]; o1[r] += sl[16 + r]; }
            ls += sl[32];
        }
        float inv = 1.0f / ls;
        int b = bh >> 4, h = bh & 15;
#pragma unroll
        for (int r = 0; r < 16; r++) {
            int crow = (r & 3) + 8 * (r >> 2) + 4 * hi;
            float ibc = __shfl(inv, crow);
            size_t base = ((size_t)(b * 2048 + q0 + crow)) * 1024 + h * 64;
            Ob[base + ql] = (__bf16)(o0[r] * ibc);
            Ob[base + 32 + ql] = (__bf16)(o1[r] * ibc);
        }
    }
}

// ---------------------------------------------------------------------------
// launch
// ---------------------------------------------------------------------------
extern "C" void kernel_launch(void* const* d_in, const int* in_sizes, int n_in,
                              void* d_out, int out_size, void* d_ws, size_t ws_size,
                              hipStream_t stream) {
    const float* x = (const float*)d_in[0];       // (2, 2048, 1024)
    const float* w_qkv = (const float*)d_in[1];   // (1024, 3072)
    const float* w_out = (const float*)d_in[2];   // (1024, 1024)
    float* out = (float*)d_out;                   // (2, 2048, 1024)

    char* ws = (char*)d_ws;
    __bf16* xb    = (__bf16*)(ws);                        //  8 MB (4096x1024)
    __bf16* wqkvT = (__bf16*)(ws + (size_t)(8  << 20));   //  6 MB (3072x1024)
    __bf16* woutT = (__bf16*)(ws + (size_t)(14 << 20));   //  2 MB (1024x1024)
    __bf16* Qf    = (__bf16*)(ws + (size_t)(16 << 20));   //  8 MB
    __bf16* Kf    = (__bf16*)(ws + (size_t)(24 << 20));   //  8 MB
    __bf16* Vf    = (__bf16*)(ws + (size_t)(32 << 20));   //  8 MB
    __bf16* Ob    = (__bf16*)(ws + (size_t)(40 << 20));   //  8 MB (4096x1024)

    cvt_f32_bf16<<<4096, 256, 0, stream>>>(x, xb, 4096 * 1024 / 4);
    transpose_bf16<<<dim3(3072 / 32, 1024 / 32), dim3(32, 8), 0, stream>>>(w_qkv, wqkvT, 1024, 3072);
    transpose_bf16<<<dim3(1024 / 32, 1024 / 32), dim3(32, 8), 0, stream>>>(w_out, woutT, 1024, 1024);
    // QKV projection (M=3072 feats, N=4096 tokens)
    gemm_bt<1><<<768, 256, 0, stream>>>(
        wqkvT, xb, 3072, 4096, 1024, nullptr, Qf, Kf, Vf);
    attn_fwd7<<<2048, 256, 0, stream>>>(Qf, Kf, Vf, Ob);
    // output projection (M=1024 feats, N=4096 tokens)
    gemm_bt<0><<<256, 256, 0, stream>>>(
        woutT, Ob, 1024, 4096, 1024, out, nullptr, nullptr, nullptr);
}

// Round 9
// 107.319 us; speedup vs baseline: 1.0743x; 1.0434x over previous
//
#include <hip/hip_runtime.h>

typedef __attribute__((ext_vector_type(4))) float f32x4;
typedef __attribute__((ext_vector_type(16))) float f32x16;
typedef __attribute__((ext_vector_type(8))) __bf16 bf16x8;
typedef __attribute__((ext_vector_type(4))) __bf16 bf16x4;
typedef __attribute__((ext_vector_type(4))) unsigned u32x4;
typedef __attribute__((ext_vector_type(2))) unsigned u32x2;

static __device__ __forceinline__ f32x4 mfma16(bf16x8 a, bf16x8 b, f32x4 c) {
    return __builtin_amdgcn_mfma_f32_16x16x32_bf16(a, b, c, 0, 0, 0);
}
static __device__ __forceinline__ f32x16 mfma32(bf16x8 a, bf16x8 b, f32x16 c) {
    return __builtin_amdgcn_mfma_f32_32x32x16_bf16(a, b, c, 0, 0, 0);
}
static __device__ __forceinline__ unsigned pk_bf16(float a, float b) {
    unsigned lo = __builtin_bit_cast(unsigned short, (__bf16)a);
    unsigned hh = __builtin_bit_cast(unsigned short, (__bf16)b);
    return lo | (hh << 16);
}

// Q pre-scale: 1/sqrt(64) * log2(e)  (exp2 applied directly to S, shift-free)
#define QSCALE 0.18033688f

// ---------------------------------------------------------------------------
// 1) fused prep: x cvt -> bf16 (blocks 0..4095), w_qkv transpose
//    (4096..7167), w_out transpose (7168..8191)
// ---------------------------------------------------------------------------
__global__ __launch_bounds__(256) void prep_all(const float* __restrict__ x,
                                                __bf16* __restrict__ xb,
                                                const float* __restrict__ wq,
                                                __bf16* __restrict__ wqT,
                                                const float* __restrict__ wo,
                                                __bf16* __restrict__ woT) {
    __shared__ float t[32][33];
    int bid = blockIdx.x, tid = threadIdx.x;
    if (bid < 4096) {
        int i = bid * 256 + tid;
        f32x4 v = ((const f32x4*)x)[i];
        bf16x4 o;
#pragma unroll
        for (int j = 0; j < 4; j++) o[j] = (__bf16)v[j];
        ((bf16x4*)xb)[i] = o;
        return;
    }
    const float* in;
    __bf16* out;
    int R, C, bx, by;
    if (bid < 4096 + 3072) {
        int b2 = bid - 4096;
        in = wq; out = wqT; R = 1024; C = 3072;
        bx = (b2 % 96) * 32; by = (b2 / 96) * 32;
    } else {
        int b2 = bid - 7168;
        in = wo; out = woT; R = 1024; C = 1024;
        bx = (b2 % 32) * 32; by = (b2 / 32) * 32;
    }
    int tx = tid & 31, ty = tid >> 5;  // 32 x 8
#pragma unroll
    for (int k = 0; k < 32; k += 8)
        t[ty + k][tx] = in[(size_t)(by + ty + k) * C + bx + tx];
    __syncthreads();
#pragma unroll
    for (int k = 0; k < 32; k += 8)
        out[(size_t)(bx + ty + k) * R + by + tx] = (__bf16)t[tx][ty + k];
}

// ---------------------------------------------------------------------------
// 3) bf16 GEMM (round-5 proven): orientation-B, 128x128 tile, BK=64, 4 waves,
//    single-buffer 2-barrier K-loop. MODE 0: fp32 float4 stores.
//    MODE 1: scatter QKV fragments (Q scaled; Qf/Kf bf16x4, Vf scalar).
// ---------------------------------------------------------------------------
#define BM 128
#define BN 128
#define BKG 64

template <int MODE>
__global__ __launch_bounds__(256) void gemm_bt(const __bf16* __restrict__ A,
                                               const __bf16* __restrict__ Bt,
                                               int M, int N, int K,
                                               float* __restrict__ Cout,
                                               __bf16* __restrict__ Qf,
                                               __bf16* __restrict__ Kf,
                                               __bf16* __restrict__ Vf) {
    __shared__ __attribute__((aligned(16))) __bf16 As[BM * BKG];
    __shared__ __attribute__((aligned(16))) __bf16 Bs[BN * BKG];
    int tid = threadIdx.x;
    int wave = tid >> 6, lane = tid & 63;
    int lrow = lane & 15, lgrp = lane >> 4;
    int chunk = gridDim.x >> 3;
    int bid = blockIdx.x;
    int swz = (bid & 7) * chunk + (bid >> 3);
    int nbx = N >> 7;
    int m0 = (swz / nbx) * BM, n0 = (swz % nbx) * BN;
    int wm = (wave >> 1) * 64, wn = (wave & 1) * 64;

    f32x4 acc[4][4];
#pragma unroll
    for (int i = 0; i < 4; i++)
#pragma unroll
        for (int j = 0; j < 4; j++) acc[i][j] = (f32x4){0.f, 0.f, 0.f, 0.f};

    int srow = tid >> 3;
    int gch = (tid & 7) ^ (srow & 7);
    const __bf16* aSrc = A + (size_t)(m0 + srow) * K + gch * 8;
    const __bf16* bSrc = Bt + (size_t)(n0 + srow) * K + gch * 8;

    for (int k0 = 0; k0 < K; k0 += BKG) {
#pragma unroll
        for (int c = 0; c < 4; c++) {
            __builtin_amdgcn_global_load_lds(
                (const __attribute__((address_space(1))) void*)(aSrc + k0 + (size_t)c * 32 * K),
                (__attribute__((address_space(3))) void*)(As + (c * 256 + wave * 64) * 8),
                16, 0, 0);
        }
#pragma unroll
        for (int c = 0; c < 4; c++) {
            __builtin_amdgcn_global_load_lds(
                (const __attribute__((address_space(1))) void*)(bSrc + k0 + (size_t)c * 32 * K),
                (__attribute__((address_space(3))) void*)(Bs + (c * 256 + wave * 64) * 8),
                16, 0, 0);
        }
        __syncthreads();
#pragma unroll
        for (int kk = 0; kk < 2; kk++) {
            bf16x8 af[4], bfr[4];
#pragma unroll
            for (int mt = 0; mt < 4; mt++) {
                int row = wm + mt * 16 + lrow;
                int slot = row * 8 + ((4 * kk + lgrp) ^ (row & 7));
                af[mt] = *(const bf16x8*)(As + slot * 8);
            }
#pragma unroll
            for (int nt = 0; nt < 4; nt++) {
                int row = wn + nt * 16 + lrow;
                int slot = row * 8 + ((4 * kk + lgrp) ^ (row & 7));
                bfr[nt] = *(const bf16x8*)(Bs + slot * 8);
            }
#pragma unroll
            for (int mt = 0; mt < 4; mt++)
#pragma unroll
                for (int nt = 0; nt < 4; nt++)
                    acc[mt][nt] = mfma16(af[mt], bfr[nt], acc[mt][nt]);
        }
        __syncthreads();
    }

#pragma unroll
    for (int mt = 0; mt < 4; mt++) {
#pragma unroll
        for (int nt = 0; nt < 4; nt++) {
            int f0 = m0 + wm + mt * 16 + lgrp * 4;
            int t = n0 + wn + nt * 16 + lrow;
            if (MODE == 0) {
                *(f32x4*)(Cout + (size_t)t * M + f0) = acc[mt][nt];
            } else {
                int which = f0 >> 10, hn = f0 & 1023;
                int h = hn >> 6, d0 = hn & 63;
                int b = t >> 11, li = t & 2047;
                int bh = b * 16 + h, c = li >> 5, tl = li & 31;
                size_t bhbase = (size_t)bh * 131072;
                if (which == 2) {
                    int ks = tl >> 4, hv = (tl >> 3) & 1, jv = tl & 7;
                    size_t base =
                        bhbase + ((size_t)(c * 4 + ks * 2 + hv) * 64 + d0) * 8 + jv;
#pragma unroll
                    for (int r = 0; r < 4; r++)
                        Vf[base + (size_t)r * 8] = (__bf16)acc[mt][nt][r];
                } else {
                    int st = d0 >> 4, hv = (d0 >> 3) & 1, j0 = d0 & 7;
                    size_t idx =
                        bhbase + ((size_t)(c * 8 + st * 2 + hv) * 32 + tl) * 8 + j0;
                    bf16x4 pv;
                    if (which == 0) {
#pragma unroll
                        for (int r = 0; r < 4; r++)
                            pv[r] = (__bf16)(acc[mt][nt][r] * QSCALE);
                        *(bf16x4*)(Qf + idx) = pv;
                    } else {
#pragma unroll
                        for (int r = 0; r < 4; r++) pv[r] = (__bf16)acc[mt][nt][r];
                        *(bf16x4*)(Kf + idx) = pv;
                    }
                }
            }
        }
    }
}

// ---------------------------------------------------------------------------
// 4) Causal flash attention, swapped-QK^T, 32x32x16 MFMA, fragment-swizzled
//    Q/K/V. 2048 blocks (one 32-row strip), 4 waves split chunk PAIRS:
//    each iteration computes TWO adjacent chunks with independent dep chains
//    (ILP-2) -- one chunk's MFMA/TRANS fills the other's stalls.
//    Shift-free softmax => partial (O, ls) combine is a pure SUM.
// ---------------------------------------------------------------------------
template <bool MASKED>
static __device__ __forceinline__ void attn_one(
    int c, int ql, int hi, const __bf16* __restrict__ Kp,
    const __bf16* __restrict__ Vp, const bf16x8 (&qf)[4],
    f32x16& o0, f32x16& o1, float& ls) {
    const __bf16* kb = Kp + ((size_t)c * 8 + hi) * 256 + ql * 8;
    bf16x8 kf[4];
#pragma unroll
    for (int st = 0; st < 4; st++) kf[st] = *(const bf16x8*)(kb + st * 512);
    const __bf16* vb = Vp + ((size_t)c * 4 + hi) * 512 + ql * 8;
    bf16x8 v00 = *(const bf16x8*)(vb);
    bf16x8 v01 = *(const bf16x8*)(vb + 256);
    bf16x8 v10 = *(const bf16x8*)(vb + 1024);
    bf16x8 v11 = *(const bf16x8*)(vb + 1280);

    f32x16 sa;
#pragma unroll
    for (int r = 0; r < 16; r++) sa[r] = 0.f;
#pragma unroll
    for (int st = 0; st < 4; st++) sa = mfma32(kf[st], qf[st], sa);

    float p[16];
    float psum = 0.f;
#pragma unroll
    for (int r = 0; r < 16; r++) {
        float s = sa[r];
        if (MASKED) {
            int krel = (r & 3) + 8 * (r >> 2) + 4 * hi;
            if (krel > ql) s = -1e30f;
        }
        float pv = __builtin_amdgcn_exp2f(s);
        p[r] = pv;
        psum += pv;
    }
    u32x2 ps = __builtin_amdgcn_permlane32_swap(
        __builtin_bit_cast(unsigned, psum), __builtin_bit_cast(unsigned, psum),
        false, false);
    psum += __builtin_bit_cast(float, hi ? ps[0] : ps[1]);
    ls += psum;

    unsigned w[8];
#pragma unroll
    for (int i = 0; i < 8; i++) w[i] = pk_bf16(p[2 * i], p[2 * i + 1]);
    u32x2 r02 = __builtin_amdgcn_permlane32_swap(w[0], w[2], false, false);
    u32x2 r13 = __builtin_amdgcn_permlane32_swap(w[1], w[3], false, false);
    u32x2 r46 = __builtin_amdgcn_permlane32_swap(w[4], w[6], false, false);
    u32x2 r57 = __builtin_amdgcn_permlane32_swap(w[5], w[7], false, false);
    bf16x8 pa0 = __builtin_bit_cast(bf16x8, (u32x4){r02[0], r13[0], r02[1], r13[1]});
    bf16x8 pa1 = __builtin_bit_cast(bf16x8, (u32x4){r46[0], r57[0], r46[1], r57[1]});

    o0 = mfma32(pa0, v00, o0);
    o1 = mfma32(pa0, v01, o1);
    o0 = mfma32(pa1, v10, o0);
    o1 = mfma32(pa1, v11, o1);
}

// two adjacent full chunks, independent chains interleaved
static __device__ __forceinline__ void attn_pair(
    int cA, int ql, int hi, const __bf16* __restrict__ Kp,
    const __bf16* __restrict__ Vp, const bf16x8 (&qf)[4],
    f32x16& o0, f32x16& o1, float& ls) {
    const __bf16* kbA = Kp + ((size_t)cA * 8 + hi) * 256 + ql * 8;
    bf16x8 kA[4], kB[4];
#pragma unroll
    for (int st = 0; st < 4; st++) {
        kA[st] = *(const bf16x8*)(kbA + st * 512);
        kB[st] = *(const bf16x8*)(kbA + 2048 + st * 512);
    }
    const __bf16* vbA = Vp + ((size_t)cA * 4 + hi) * 512 + ql * 8;
    bf16x8 vA00 = *(const bf16x8*)(vbA);
    bf16x8 vA01 = *(const bf16x8*)(vbA + 256);
    bf16x8 vA10 = *(const bf16x8*)(vbA + 1024);
    bf16x8 vA11 = *(const bf16x8*)(vbA + 1280);
    bf16x8 vB00 = *(const bf16x8*)(vbA + 2048);
    bf16x8 vB01 = *(const bf16x8*)(vbA + 2048 + 256);
    bf16x8 vB10 = *(const bf16x8*)(vbA + 2048 + 1024);
    bf16x8 vB11 = *(const bf16x8*)(vbA + 2048 + 1280);

    f32x16 saA, saB;
#pragma unroll
    for (int r = 0; r < 16; r++) { saA[r] = 0.f; saB[r] = 0.f; }
#pragma unroll
    for (int st = 0; st < 4; st++) {
        saA = mfma32(kA[st], qf[st], saA);
        saB = mfma32(kB[st], qf[st], saB);
    }

    float pA[16], pB[16];
    float psum = 0.f;
#pragma unroll
    for (int r = 0; r < 16; r++) {
        float a = __builtin_amdgcn_exp2f(saA[r]);
        float b = __builtin_amdgcn_exp2f(saB[r]);
        pA[r] = a; pB[r] = b;
        psum += a + b;
    }
    u32x2 ps = __builtin_amdgcn_permlane32_swap(
        __builtin_bit_cast(unsigned, psum), __builtin_bit_cast(unsigned, psum),
        false, false);
    psum += __builtin_bit_cast(float, hi ? ps[0] : ps[1]);
    ls += psum;

    unsigned wA[8], wB[8];
#pragma unroll
    for (int i = 0; i < 8; i++) {
        wA[i] = pk_bf16(pA[2 * i], pA[2 * i + 1]);
        wB[i] = pk_bf16(pB[2 * i], pB[2 * i + 1]);
    }
    u32x2 a02 = __builtin_amdgcn_permlane32_swap(wA[0], wA[2], false, false);
    u32x2 a13 = __builtin_amdgcn_permlane32_swap(wA[1], wA[3], false, false);
    u32x2 a46 = __builtin_amdgcn_permlane32_swap(wA[4], wA[6], false, false);
    u32x2 a57 = __builtin_amdgcn_permlane32_swap(wA[5], wA[7], false, false);
    u32x2 b02 = __builtin_amdgcn_permlane32_swap(wB[0], wB[2], false, false);
    u32x2 b13 = __builtin_amdgcn_permlane32_swap(wB[1], wB[3], false, false);
    u32x2 b46 = __builtin_amdgcn_permlane32_swap(wB[4], wB[6], false, false);
    u32x2 b57 = __builtin_amdgcn_permlane32_swap(wB[5], wB[7], false, false);
    bf16x8 paA0 = __builtin_bit_cast(bf16x8, (u32x4){a02[0], a13[0], a02[1], a13[1]});
    bf16x8 paA1 = __builtin_bit_cast(bf16x8, (u32x4){a46[0], a57[0], a46[1], a57[1]});
    bf16x8 paB0 = __builtin_bit_cast(bf16x8, (u32x4){b02[0], b13[0], b02[1], b13[1]});
    bf16x8 paB1 = __builtin_bit_cast(bf16x8, (u32x4){b46[0], b57[0], b46[1], b57[1]});

    o0 = mfma32(paA0, vA00, o0);
    o1 = mfma32(paA0, vA01, o1);
    o0 = mfma32(paB0, vB00, o0);
    o1 = mfma32(paB0, vB01, o1);
    o0 = mfma32(paA1, vA10, o0);
    o1 = mfma32(paA1, vA11, o1);
    o0 = mfma32(paB1, vB10, o0);
    o1 = mfma32(paB1, vB11, o1);
}

__global__ __launch_bounds__(256, 1) void attn_fwd8(const __bf16* __restrict__ Qf,
                                                    const __bf16* __restrict__ Kf,
                                                    const __bf16* __restrict__ Vf,
                                                    __bf16* __restrict__ Ob) {
    __shared__ float comb[3][64][33];
    int tid = threadIdx.x;
    int wave = tid >> 6, lane = tid & 63;
    int ql = lane & 31, hi = lane >> 5;
    // XCD swizzle: 2048 blocks = 8 xcd x 4 heads x 64 strips (heavy first)
    int bid = blockIdx.x;
    int xcd = bid & 7, idx = bid >> 3;
    int bh = xcd * 4 + (idx >> 6);
    int strip = 63 - (idx & 63);
    int q0 = strip * 32;

    const __bf16* Qp = Qf + (size_t)bh * 131072;
    const __bf16* Kp = Kf + (size_t)bh * 131072;
    const __bf16* Vp = Vf + (size_t)bh * 131072;

    const __bf16* qb = Qp + ((size_t)strip * 8 + hi) * 256 + ql * 8;
    bf16x8 qf[4];
#pragma unroll
    for (int st = 0; st < 4; st++) qf[st] = *(const bf16x8*)(qb + st * 512);

    f32x16 o0, o1;
#pragma unroll
    for (int r = 0; r < 16; r++) { o0[r] = 0.f; o1[r] = 0.f; }
    float ls = 0.f;

    // full-chunk pairs p -> chunks (2p, 2p+1); pair p owned by wave p%4
    int npair = strip >> 1;
    for (int p = wave; p < npair; p += 4)
        attn_pair(2 * p, ql, hi, Kp, Vp, qf, o0, o1, ls);
    // leftover full chunk (strip odd) -> least-loaded wave
    if ((strip & 1) && ((npair & 3) == wave))
        attn_one<false>(strip - 1, ql, hi, Kp, Vp, qf, o0, o1, ls);
    // masked diagonal chunk -> next wave after leftover
    if ((((npair + (strip & 1)) & 3)) == wave)
        attn_one<true>(strip, ql, hi, Kp, Vp, qf, o0, o1, ls);

    // ---- combine partials: waves 1..3 -> slabs, single barrier, wave 0 sums
    if (wave >= 1) {
        float* sl = &comb[wave - 1][lane][0];
#pragma unroll
        for (int r = 0; r < 16; r++) { sl[r] = o0[r]; sl[16 + r] = o1[r]; }
        sl[32] = ls;
    }
    __syncthreads();
    if (wave == 0) {
#pragma unroll
        for (int s = 0; s < 3; s++) {
            const float* sl = &comb[s][lane][0];
#pragma unroll
            for (int r = 0; r < 16; r++) { o0[r] += sl[r]; o1[r] += sl[16 + r]; }
            ls += sl[32];
        }
        float inv = 1.0f / ls;
        int b = bh >> 4, h = bh & 15;
#pragma unroll
        for (int r = 0; r < 16; r++) {
            int crow = (r & 3) + 8 * (r >> 2) + 4 * hi;
            float ibc = __shfl(inv, crow);
            size_t base = ((size_t)(b * 2048 + q0 + crow)) * 1024 + h * 64;
            Ob[base + ql] = (__bf16)(o0[r] * ibc);
            Ob[base + 32 + ql] = (__bf16)(o1[r] * ibc);
        }
    }
}

// ---------------------------------------------------------------------------
// launch
// ---------------------------------------------------------------------------
extern "C" void kernel_launch(void* const* d_in, const int* in_sizes, int n_in,
                              void* d_out, int out_size, void* d_ws, size_t ws_size,
                              hipStream_t stream) {
    const float* x = (const float*)d_in[0];       // (2, 2048, 1024)
    const float* w_qkv = (const float*)d_in[1];   // (1024, 3072)
    const float* w_out = (const float*)d_in[2];   // (1024, 1024)
    float* out = (float*)d_out;                   // (2, 2048, 1024)

    char* ws = (char*)d_ws;
    __bf16* xb    = (__bf16*)(ws);                        //  8 MB (4096x1024)
    __bf16* wqkvT = (__bf16*)(ws + (size_t)(8  << 20));   //  6 MB (3072x1024)
    __bf16* woutT = (__bf16*)(ws + (size_t)(14 << 20));   //  2 MB (1024x1024)
    __bf16* Qf    = (__bf16*)(ws + (size_t)(16 << 20));   //  8 MB
    __bf16* Kf    = (__bf16*)(ws + (size_t)(24 << 20));   //  8 MB
    __bf16* Vf    = (__bf16*)(ws + (size_t)(32 << 20));   //  8 MB
    __bf16* Ob    = (__bf16*)(ws + (size_t)(40 << 20));   //  8 MB (4096x1024)

    prep_all<<<8192, 256, 0, stream>>>(x, xb, w_qkv, wqkvT, w_out, woutT);
    // QKV projection (M=3072 feats, N=4096 tokens)
    gemm_bt<1><<<768, 256, 0, stream>>>(
        wqkvT, xb, 3072, 4096, 1024, nullptr, Qf, Kf, Vf);
    attn_fwd8<<<2048, 256, 0, stream>>>(Qf, Kf, Vf, Ob);
    // output projection (M=1024 feats, N=4096 tokens)
    gemm_bt<0><<<256, 256, 0, stream>>>(
        woutT, Ob, 1024, 4096, 1024, out, nullptr, nullptr, nullptr);
}